// Round 8
// baseline (151.459 us; speedup 1.0000x reference)
//
#include <hip/hip_runtime.h>
#include <cstdint>

// ---------------------------------------------------------------------------
// ObjectBoxDetect via bf16 MFMA. out[16,8400,85] fp32.
//   L0: x[16,256,80,80]  W[85,256]  stride 8   anchors [0,6400)
//   L1: x[16,512,40,40]  W[85,512]  stride 16  anchors [6400,8000)
//   L2: x[16,1024,20,20] W[85,1024] stride 32  anchors [8000,8400)
//
// Round-8: r7's level-interleave was the regression (long L2 blocks started
// late -> +~13us makespan). Revert to heaviest-first (r6). Keep 2-deep B
// pipeline; add 2-deep A prefetch (A(ks+2) issued at iter ks, consumed at
// ks+2 -> ~2 ksteps of slack vs ~900cy HBM latency). Manual 2-step loop
// body keeps buffer parity compile-time-static (no runtime-indexed arrays).
// ---------------------------------------------------------------------------

typedef __attribute__((ext_vector_type(8))) short bf16x8;
typedef __attribute__((ext_vector_type(4))) float f32x4;

constexpr int KS0 = 8, KS1 = 16, KS2 = 32;            // K-steps per level (C/32)
constexpr int F0 = 6 * KS0, F1 = 6 * KS1, F2 = 6 * KS2;
constexpr int FOFF0 = 0, FOFF1 = F0, FOFF2 = F0 + F1;
constexpr int NFRAG = F0 + F1 + F2;                    // 336 fragments
constexpr size_t BIAS_OFF = 0;                         // 3*96 floats = 1152 B
constexpr size_t BPK_OFF  = 1152;                      // 16B aligned
constexpr size_t WS_NEED  = BPK_OFF + (size_t)NFRAG * 64 * 16;

__device__ __forceinline__ unsigned short f2bf(float f) {
    union { float f; unsigned u; } v; v.f = f;
    unsigned r = v.u + 0x7FFF + ((v.u >> 16) & 1);     // round-to-nearest-even
    return (unsigned short)(r >> 16);
}

// Pack W[o][c] -> bf16 B-fragments ([ks][n]-major per level) + padded bias.
// B frag layout (16x16x32): lane l holds col o = n*16+(l&15),
// k-slots c = ks*32 + (l>>4)*8 + e.
__global__ __launch_bounds__(256) void prep_pack(
    const float* __restrict__ W0, const float* __restrict__ W1,
    const float* __restrict__ W2,
    const float* __restrict__ b0, const float* __restrict__ b1,
    const float* __restrict__ b2,
    unsigned char* __restrict__ ws)
{
    int t = blockIdx.x * 256 + threadIdx.x;
    if (t < 288) {
        int lvl = t / 96, o = t % 96;
        const float* bp = (lvl == 0) ? b0 : (lvl == 1) ? b1 : b2;
        ((float*)(ws + BIAS_OFF))[t] = (o < 85) ? bp[o] : 0.0f;
    }
    if (t >= NFRAG * 64) return;
    int frag = t >> 6, l = t & 63;
    int C; const float* W; int f;
    if (frag < FOFF1)      { C = 256;  W = W0; f = frag;         }
    else if (frag < FOFF2) { C = 512;  W = W1; f = frag - FOFF1; }
    else                   { C = 1024; W = W2; f = frag - FOFF2; }
    int ks = f / 6, n = f % 6;                          // [ks][n]-major
    int o  = n * 16 + (l & 15);
    int c0 = ks * 32 + (l >> 4) * 8;
    bf16x8 r;
#pragma unroll
    for (int e = 0; e < 8; ++e)
        r[e] = (o < 85) ? (short)f2bf(W[(size_t)o * C + c0 + e]) : (short)0;
    ((bf16x8*)(ws + BPK_OFF))[frag * 64 + l] = r;
}

template <int C, int HW, int NX, int LEVEL, int AOFF, int KSTEPS, int FOFF>
__device__ __forceinline__ void mfma_level(
    const float* __restrict__ feat, const unsigned char* __restrict__ ws,
    float* __restrict__ out, int blk, uint4* __restrict__ Bsm /* [2][384] */)
{
    const int tid = threadIdx.x;
    const int w   = tid >> 6;
    const int l   = tid & 63;
    const int col = l & 15;            // output col within 16-tile
    const int kg  = l >> 4;            // k-group
    const bool lo_half = (tid < 128);  // uniform per wave

    // one 16-pos M-subtile per wave; HW % 16 == 0 so it stays in one batch.
    const int p0  = blk * 64 + w * 16;
    const int b   = p0 / HW;
    const int hw0 = p0 - b * HW;
    const float* fb = feat + (size_t)b * C * HW + hw0;

    const float* bias = (const float*)(ws + BIAS_OFF) + LEVEL * 96;
    const uint4* bsrc = (const uint4*)(ws + BPK_OFF) + (size_t)FOFF * 64;

    f32x4 acc[6];
#pragma unroll
    for (int n = 0; n < 6; ++n) {
        float bv = bias[n * 16 + col];
        f32x4 z = { bv, bv, bv, bv };
        acc[n] = z;
    }

    // ---- prologue ----
    // B(0) straight into LDS buf 0
    {
        const uint4* s = bsrc;
        Bsm[tid] = s[tid];
        if (lo_half) Bsm[256 + tid] = s[256 + tid];
    }
    // A(0) -> flA0, A(1) -> flA1
    float flA0[8], flA1[8];
    {
        const float* p = fb + col + (size_t)(kg * 8) * HW;
#pragma unroll
        for (int e = 0; e < 8; ++e) flA0[e] = p[(size_t)e * HW];
    }
    if (KSTEPS > 1) {
        const float* p = fb + col + (size_t)(32 + kg * 8) * HW;
#pragma unroll
        for (int e = 0; e < 8; ++e) flA1[e] = p[(size_t)e * HW];
    }
    // B(1) -> pend regs (ds_written inside iter 0)
    uint4 pb0, pb1;
    if (KSTEPS > 1) {
        const uint4* s = bsrc + 384;
        pb0 = s[tid];
        if (lo_half) pb1 = s[256 + tid];
    }
    __syncthreads();

    // one k-step; all buffer parity is compile-time via the 2-step caller.
    auto step = [&](int ks, float (&flAc)[8], uint4* bufCur, uint4* bufNxt)
        __attribute__((always_inline)) -> void
    {
        // 1. ds_write pend B(ks+1) (its global loads issued a full kstep ago)
        if (ks + 1 < KSTEPS) {
            bufNxt[tid] = pb0;
            if (lo_half) bufNxt[256 + tid] = pb1;
        }
        // 2. issue B(ks+2) global loads into pend regs
        if (ks + 2 < KSTEPS) {
            const uint4* s = bsrc + (size_t)(ks + 2) * 384;
            pb0 = s[tid];
            if (lo_half) pb1 = s[256 + tid];
        }
        // 3. cvt A(ks) -> bf16 fragment
        bf16x8 a;
#pragma unroll
        for (int e = 0; e < 8; ++e) a[e] = (short)f2bf(flAc[e]);
        // 4. issue A(ks+2) loads into the slot just consumed
        if (ks + 2 < KSTEPS) {
            const float* p = fb + col + (size_t)((ks + 2) * 32 + kg * 8) * HW;
#pragma unroll
            for (int e = 0; e < 8; ++e) flAc[e] = p[(size_t)e * HW];
        }
        // 5. B(ks) from LDS + MFMA
        const bf16x8* bl = (const bf16x8*)bufCur;
#pragma unroll
        for (int n = 0; n < 6; ++n) {
            bf16x8 bq = bl[n * 64 + l];
            acc[n] = __builtin_amdgcn_mfma_f32_16x16x32_bf16(a, bq, acc[n], 0, 0, 0);
        }
        // 6. one barrier per kstep
        __syncthreads();
    };

    uint4* buf0 = Bsm;
    uint4* buf1 = Bsm + 384;
#pragma unroll 1
    for (int ks = 0; ks < KSTEPS; ks += 2) {   // KSTEPS is even for all levels
        step(ks,     flA0, buf0, buf1);
        step(ks + 1, flA1, buf1, buf0);
    }

    // Epilogue. C/D layout (m89-verified): col = l&15, row = (l>>4)*4 + j.
    constexpr float S  = (float)(8 << LEVEL);
    constexpr float P4 = 4.0f * (float)(1 << LEVEL);
#pragma unroll
    for (int j = 0; j < 4; ++j) {
        const int hw = hw0 + kg * 4 + j;
        float sg[6];
#pragma unroll
        for (int n = 0; n < 6; ++n) {
            float v = acc[n][j];
            sg[n] = __builtin_amdgcn_rcpf(1.0f + __expf(-v));
        }
        const int grp = l & 48;
        float y0 = __shfl(sg[0], grp + 0);
        float y1 = __shfl(sg[0], grp + 1);
        float y2 = __shfl(sg[0], grp + 2);
        float y3 = __shfl(sg[0], grp + 3);
        float wx = (float)(hw % NX);
        float wy = (float)(hw / NX);
        float d0 = y0 * y0 * P4, d1 = y1 * y1 * P4;
        float d2 = y2 * y2 * P4, d3 = y3 * y3 * P4;
        float x1 = (wx + 1.0f - d0) * S;
        float yA = (wy + 1.0f - d1) * S;
        float x2 = (wx + d2) * S;
        float yB = (wy + d3) * S;
        float bx = (x1 + x2) * 0.5f, by = (yA + yB) * 0.5f;
        float bw = x2 - x1,          bh = yB - yA;
        sg[0] = (col == 0) ? bx : (col == 1) ? by
              : (col == 2) ? bw : (col == 3) ? bh : sg[0];
        float* op = out + ((size_t)b * 8400 + AOFF + hw) * 85;
#pragma unroll
        for (int n = 0; n < 6; ++n) {
            int o = n * 16 + col;
            if (o < 85) op[o] = sg[n];
        }
    }
}

// Grid: 2100 blocks of 64 positions, heaviest-first (longest-job-first:
// all 100 L2 blocks, 32 ksteps each, dispatch at t=0).
__global__ __launch_bounds__(256, 8) void detect_mfma(
    const float* __restrict__ x0, const float* __restrict__ x1,
    const float* __restrict__ x2,
    const unsigned char* __restrict__ ws, float* __restrict__ out)
{
    __shared__ uint4 Bsm[2 * 384];     // 12 KB double-buffered B stage
    int blk = blockIdx.x;
    if (blk < 100)      mfma_level<1024, 400,  20, 2, 8000, KS2, FOFF2>(x2, ws, out, blk,       Bsm);
    else if (blk < 500) mfma_level<512,  1600, 40, 1, 6400, KS1, FOFF1>(x1, ws, out, blk - 100, Bsm);
    else                mfma_level<256,  6400, 80, 0, 0,    KS0, FOFF0>(x0, ws, out, blk - 500, Bsm);
}

// ---------------- fallback (ws too small): round-2 VALU path ----------------
template <int C, int HW, int NX, int LEVEL, int ONUM, bool BOX>
__device__ __forceinline__ void decode_path_fb(
    const float* __restrict__ feat, const float* __restrict__ Wm,
    const float* __restrict__ bias, float* __restrict__ out,
    int o_lo_in, int pos)
{
    const int o_lo = __builtin_amdgcn_readfirstlane(o_lo_in);
    const int b  = pos / HW;
    const int hw = pos - b * HW;
    const float* fp = feat + (size_t)b * (C * HW) + hw;
    float acc[ONUM];
#pragma unroll
    for (int j = 0; j < ONUM; ++j) acc[j] = bias[o_lo + j];
#pragma unroll 4
    for (int c = 0; c < C; ++c) {
        float fv = fp[(size_t)c * HW];
#pragma unroll
        for (int j = 0; j < ONUM; ++j)
            acc[j] = fmaf(fv, Wm[(o_lo + j) * C + c], acc[j]);
    }
#pragma unroll
    for (int j = 0; j < ONUM; ++j)
        acc[j] = __builtin_amdgcn_rcpf(1.0f + __expf(-acc[j]));
    constexpr float S = (float)(8 << LEVEL);
    constexpr int AOFF = (LEVEL == 0) ? 0 : ((LEVEL == 1) ? 6400 : 8000);
    float* op = out + ((size_t)b * 8400 + AOFF + hw) * 85 + o_lo;
    if constexpr (BOX) {
        constexpr float P4 = 4.0f * (float)(1 << LEVEL);
        float wx = (float)(hw % NX), wy = (float)(hw / NX);
        float d0 = acc[0] * acc[0] * P4, d1 = acc[1] * acc[1] * P4;
        float d2 = acc[2] * acc[2] * P4, d3 = acc[3] * acc[3] * P4;
        float x1 = (wx + 1.0f - d0) * S, y1 = (wy + 1.0f - d1) * S;
        float x2 = (wx + d2) * S,        y2 = (wy + d3) * S;
        op[0] = (x1 + x2) * 0.5f; op[1] = (y1 + y2) * 0.5f;
        op[2] = x2 - x1;          op[3] = y2 - y1;
#pragma unroll
        for (int j = 4; j < ONUM; ++j) op[j] = acc[j];
    } else {
#pragma unroll
        for (int j = 0; j < ONUM; ++j) op[j] = acc[j];
    }
}

template <int C, int HW, int NX, int LEVEL>
__device__ __forceinline__ void level_block_fb(
    const float* __restrict__ feat, const float* __restrict__ Wm,
    const float* __restrict__ bias, float* __restrict__ out, int bb)
{
    const int wave = threadIdx.x >> 6, lane = threadIdx.x & 63;
    const int pos = bb * 64 + lane;
    if      (wave == 0) decode_path_fb<C, HW, NX, LEVEL, 22, true >(feat, Wm, bias, out, 0,  pos);
    else if (wave == 1) decode_path_fb<C, HW, NX, LEVEL, 22, false>(feat, Wm, bias, out, 22, pos);
    else if (wave == 2) decode_path_fb<C, HW, NX, LEVEL, 22, false>(feat, Wm, bias, out, 44, pos);
    else                decode_path_fb<C, HW, NX, LEVEL, 19, false>(feat, Wm, bias, out, 66, pos);
}

__global__ __launch_bounds__(256) void detect_fallback(
    const float* __restrict__ x0, const float* __restrict__ x1,
    const float* __restrict__ x2,
    const float* __restrict__ w0, const float* __restrict__ w1,
    const float* __restrict__ w2,
    const float* __restrict__ b0, const float* __restrict__ b1,
    const float* __restrict__ b2, float* __restrict__ out)
{
    const int blk = blockIdx.x;
    if (blk < 100)      level_block_fb<1024, 400,  20, 2>(x2, w2, b2, out, blk);
    else if (blk < 500) level_block_fb<512,  1600, 40, 1>(x1, w1, b1, out, blk - 100);
    else                level_block_fb<256,  6400, 80, 0>(x0, w0, b0, out, blk - 500);
}

extern "C" void kernel_launch(void* const* d_in, const int* in_sizes, int n_in,
                              void* d_out, int out_size, void* d_ws, size_t ws_size,
                              hipStream_t stream)
{
    const float* x0 = (const float*)d_in[0];
    const float* x1 = (const float*)d_in[1];
    const float* x2 = (const float*)d_in[2];
    const float* W0 = (const float*)d_in[3];
    const float* b0 = (const float*)d_in[4];
    const float* W1 = (const float*)d_in[5];
    const float* b1 = (const float*)d_in[6];
    const float* W2 = (const float*)d_in[7];
    const float* b2 = (const float*)d_in[8];
    float* out = (float*)d_out;

    if (ws_size >= WS_NEED) {
        unsigned char* ws = (unsigned char*)d_ws;
        prep_pack<<<(NFRAG * 64 + 255) / 256, 256, 0, stream>>>(W0, W1, W2, b0, b1, b2, ws);
        detect_mfma<<<2100, 256, 0, stream>>>(x0, x1, x2, ws, out);
    } else {
        detect_fallback<<<2100, 256, 0, stream>>>(x0, x1, x2, W0, W1, W2, b0, b1, b2, out);
    }
}

// Round 9
// 48.354 us; speedup vs baseline: 3.1323x; 3.1323x over previous
//
#include <hip/hip_runtime.h>
#include <cstdint>

// ---------------------------------------------------------------------------
// ObjectBoxDetect via bf16 MFMA. out[16,8400,85] fp32.
//   L0: x[16,256,80,80]  W[85,256]  stride 8   anchors [0,6400)
//   L1: x[16,512,40,40]  W[85,512]  stride 16  anchors [6400,8000)
//   L2: x[16,1024,20,20] W[85,1024] stride 32  anchors [8000,8400)
//
// Round-9: r8's 151us regression was SCRATCH SPILL (WRITE_SIZE 45->241 MB):
// __launch_bounds__(256,8) capped regs at 64/wave vs ~74 live. Same depth-2
// A/B pipeline now under __launch_bounds__(256,6) (budget ~85 regs, fits).
// Heaviest-first grid (r6 proven; r7's interleave regressed makespan).
// Explicit 2-step unrolled K-loop: all LDS buffer parity compile-time-static.
// ---------------------------------------------------------------------------

typedef __attribute__((ext_vector_type(8))) short bf16x8;
typedef __attribute__((ext_vector_type(4))) float f32x4;

constexpr int KS0 = 8, KS1 = 16, KS2 = 32;            // K-steps per level (C/32)
constexpr int F0 = 6 * KS0, F1 = 6 * KS1, F2 = 6 * KS2;
constexpr int FOFF0 = 0, FOFF1 = F0, FOFF2 = F0 + F1;
constexpr int NFRAG = F0 + F1 + F2;                    // 336 fragments
constexpr size_t BIAS_OFF = 0;                         // 3*96 floats = 1152 B
constexpr size_t BPK_OFF  = 1152;                      // 16B aligned
constexpr size_t WS_NEED  = BPK_OFF + (size_t)NFRAG * 64 * 16;

__device__ __forceinline__ unsigned short f2bf(float f) {
    union { float f; unsigned u; } v; v.f = f;
    unsigned r = v.u + 0x7FFF + ((v.u >> 16) & 1);     // round-to-nearest-even
    return (unsigned short)(r >> 16);
}

// Pack W[o][c] -> bf16 B-fragments ([ks][n]-major per level) + padded bias.
// B frag layout (16x16x32): lane l holds col o = n*16+(l&15),
// k-slots c = ks*32 + (l>>4)*8 + e.
__global__ __launch_bounds__(256) void prep_pack(
    const float* __restrict__ W0, const float* __restrict__ W1,
    const float* __restrict__ W2,
    const float* __restrict__ b0, const float* __restrict__ b1,
    const float* __restrict__ b2,
    unsigned char* __restrict__ ws)
{
    int t = blockIdx.x * 256 + threadIdx.x;
    if (t < 288) {
        int lvl = t / 96, o = t % 96;
        const float* bp = (lvl == 0) ? b0 : (lvl == 1) ? b1 : b2;
        ((float*)(ws + BIAS_OFF))[t] = (o < 85) ? bp[o] : 0.0f;
    }
    if (t >= NFRAG * 64) return;
    int frag = t >> 6, l = t & 63;
    int C; const float* W; int f;
    if (frag < FOFF1)      { C = 256;  W = W0; f = frag;         }
    else if (frag < FOFF2) { C = 512;  W = W1; f = frag - FOFF1; }
    else                   { C = 1024; W = W2; f = frag - FOFF2; }
    int ks = f / 6, n = f % 6;                          // [ks][n]-major
    int o  = n * 16 + (l & 15);
    int c0 = ks * 32 + (l >> 4) * 8;
    bf16x8 r;
#pragma unroll
    for (int e = 0; e < 8; ++e)
        r[e] = (o < 85) ? (short)f2bf(W[(size_t)o * C + c0 + e]) : (short)0;
    ((bf16x8*)(ws + BPK_OFF))[frag * 64 + l] = r;
}

template <int C, int HW, int NX, int LEVEL, int AOFF, int KSTEPS, int FOFF>
__device__ __forceinline__ void mfma_level(
    const float* __restrict__ feat, const unsigned char* __restrict__ ws,
    float* __restrict__ out, int blk, uint4* __restrict__ Bsm /* [2][384] */)
{
    const int tid = threadIdx.x;
    const int w   = tid >> 6;
    const int l   = tid & 63;
    const int col = l & 15;            // output col within 16-tile
    const int kg  = l >> 4;            // k-group
    const bool lo_half = (tid < 128);  // uniform per wave

    // one 16-pos M-subtile per wave; HW % 16 == 0 so it stays in one batch.
    const int p0  = blk * 64 + w * 16;
    const int b   = p0 / HW;
    const int hw0 = p0 - b * HW;
    const float* fb = feat + (size_t)b * C * HW + hw0;
    const float* pA = fb + col + (size_t)(kg * 8) * HW;   // per-lane A base

    const float* bias = (const float*)(ws + BIAS_OFF) + LEVEL * 96;
    const uint4* bsrc = (const uint4*)(ws + BPK_OFF) + (size_t)FOFF * 64;

    f32x4 acc[6];
#pragma unroll
    for (int n = 0; n < 6; ++n) {
        float bv = bias[n * 16 + col];
        f32x4 z = { bv, bv, bv, bv };
        acc[n] = z;
    }

    uint4* buf0 = Bsm;
    uint4* buf1 = Bsm + 384;

    // ---- prologue ----
    // B(0) straight into LDS buf0
    {
        const uint4* s = bsrc;
        buf0[tid] = s[tid];
        if (lo_half) buf0[256 + tid] = s[256 + tid];
    }
    // A(0) -> flA0, A(1) -> flA1
    float flA0[8], flA1[8];
#pragma unroll
    for (int e = 0; e < 8; ++e) flA0[e] = pA[(size_t)e * HW];
    if (KSTEPS > 1) {
        const float* p = pA + (size_t)32 * HW;
#pragma unroll
        for (int e = 0; e < 8; ++e) flA1[e] = p[(size_t)e * HW];
    }
    // B(1) -> pend regs (ds_written inside even step 0)
    uint4 pb0, pb1;
    if (KSTEPS > 1) {
        const uint4* s = bsrc + 384;
        pb0 = s[tid];
        if (lo_half) pb1 = s[256 + tid];
    }
    __syncthreads();

#pragma unroll 1
    for (int ks = 0; ks < KSTEPS; ks += 2) {   // KSTEPS even for all levels
        // ================= even step: consume buf0 / flA0 =================
        // 1. ds_write pend B(ks+1) (issued a full step ago) -> buf1
        if (ks + 1 < KSTEPS) {
            buf1[tid] = pb0;
            if (lo_half) buf1[256 + tid] = pb1;
        }
        // 2. issue B(ks+2) -> pend regs
        if (ks + 2 < KSTEPS) {
            const uint4* s = bsrc + (size_t)(ks + 2) * 384;
            pb0 = s[tid];
            if (lo_half) pb1 = s[256 + tid];
        }
        // 3. cvt A(ks)
        {
            bf16x8 a;
#pragma unroll
            for (int e = 0; e < 8; ++e) a[e] = (short)f2bf(flA0[e]);
            // 4. issue A(ks+2) into the slot just consumed
            if (ks + 2 < KSTEPS) {
                const float* p = pA + (size_t)((ks + 2) * 32) * HW;
#pragma unroll
                for (int e = 0; e < 8; ++e) flA0[e] = p[(size_t)e * HW];
            }
            // 5. MFMA from buf0
            const bf16x8* bl = (const bf16x8*)buf0;
#pragma unroll
            for (int n = 0; n < 6; ++n) {
                bf16x8 bq = bl[n * 64 + l];
                acc[n] = __builtin_amdgcn_mfma_f32_16x16x32_bf16(a, bq, acc[n], 0, 0, 0);
            }
        }
        __syncthreads();

        // ================= odd step: consume buf1 / flA1 ==================
        // 1. ds_write pend B(ks+2) -> buf0
        if (ks + 2 < KSTEPS) {
            buf0[tid] = pb0;
            if (lo_half) buf0[256 + tid] = pb1;
        }
        // 2. issue B(ks+3) -> pend regs
        if (ks + 3 < KSTEPS) {
            const uint4* s = bsrc + (size_t)(ks + 3) * 384;
            pb0 = s[tid];
            if (lo_half) pb1 = s[256 + tid];
        }
        // 3. cvt A(ks+1)
        if (ks + 1 < KSTEPS) {
            bf16x8 a;
#pragma unroll
            for (int e = 0; e < 8; ++e) a[e] = (short)f2bf(flA1[e]);
            // 4. issue A(ks+3)
            if (ks + 3 < KSTEPS) {
                const float* p = pA + (size_t)((ks + 3) * 32) * HW;
#pragma unroll
                for (int e = 0; e < 8; ++e) flA1[e] = p[(size_t)e * HW];
            }
            // 5. MFMA from buf1
            const bf16x8* bl = (const bf16x8*)buf1;
#pragma unroll
            for (int n = 0; n < 6; ++n) {
                bf16x8 bq = bl[n * 64 + l];
                acc[n] = __builtin_amdgcn_mfma_f32_16x16x32_bf16(a, bq, acc[n], 0, 0, 0);
            }
        }
        __syncthreads();
    }

    // Epilogue. C/D layout (m89-verified): col = l&15, row = (l>>4)*4 + j.
    constexpr float S  = (float)(8 << LEVEL);
    constexpr float P4 = 4.0f * (float)(1 << LEVEL);
#pragma unroll
    for (int j = 0; j < 4; ++j) {
        const int hw = hw0 + kg * 4 + j;
        float sg[6];
#pragma unroll
        for (int n = 0; n < 6; ++n) {
            float v = acc[n][j];
            sg[n] = __builtin_amdgcn_rcpf(1.0f + __expf(-v));
        }
        const int grp = l & 48;
        float y0 = __shfl(sg[0], grp + 0);
        float y1 = __shfl(sg[0], grp + 1);
        float y2 = __shfl(sg[0], grp + 2);
        float y3 = __shfl(sg[0], grp + 3);
        float wx = (float)(hw % NX);
        float wy = (float)(hw / NX);
        float d0 = y0 * y0 * P4, d1 = y1 * y1 * P4;
        float d2 = y2 * y2 * P4, d3 = y3 * y3 * P4;
        float x1 = (wx + 1.0f - d0) * S;
        float yA = (wy + 1.0f - d1) * S;
        float x2 = (wx + d2) * S;
        float yB = (wy + d3) * S;
        float bx = (x1 + x2) * 0.5f, by = (yA + yB) * 0.5f;
        float bw = x2 - x1,          bh = yB - yA;
        sg[0] = (col == 0) ? bx : (col == 1) ? by
              : (col == 2) ? bw : (col == 3) ? bh : sg[0];
        float* op = out + ((size_t)b * 8400 + AOFF + hw) * 85;
#pragma unroll
        for (int n = 0; n < 6; ++n) {
            int o = n * 16 + col;
            if (o < 85) op[o] = sg[n];
        }
    }
}

// Grid: 2100 blocks of 64 positions, heaviest-first (longest-job-first:
// all 100 L2 blocks, 32 ksteps each, dispatch at t=0).
__global__ __launch_bounds__(256, 6) void detect_mfma(
    const float* __restrict__ x0, const float* __restrict__ x1,
    const float* __restrict__ x2,
    const unsigned char* __restrict__ ws, float* __restrict__ out)
{
    __shared__ uint4 Bsm[2 * 384];     // 12 KB double-buffered B stage
    int blk = blockIdx.x;
    if (blk < 100)      mfma_level<1024, 400,  20, 2, 8000, KS2, FOFF2>(x2, ws, out, blk,       Bsm);
    else if (blk < 500) mfma_level<512,  1600, 40, 1, 6400, KS1, FOFF1>(x1, ws, out, blk - 100, Bsm);
    else                mfma_level<256,  6400, 80, 0, 0,    KS0, FOFF0>(x0, ws, out, blk - 500, Bsm);
}

// ---------------- fallback (ws too small): round-2 VALU path ----------------
template <int C, int HW, int NX, int LEVEL, int ONUM, bool BOX>
__device__ __forceinline__ void decode_path_fb(
    const float* __restrict__ feat, const float* __restrict__ Wm,
    const float* __restrict__ bias, float* __restrict__ out,
    int o_lo_in, int pos)
{
    const int o_lo = __builtin_amdgcn_readfirstlane(o_lo_in);
    const int b  = pos / HW;
    const int hw = pos - b * HW;
    const float* fp = feat + (size_t)b * (C * HW) + hw;
    float acc[ONUM];
#pragma unroll
    for (int j = 0; j < ONUM; ++j) acc[j] = bias[o_lo + j];
#pragma unroll 4
    for (int c = 0; c < C; ++c) {
        float fv = fp[(size_t)c * HW];
#pragma unroll
        for (int j = 0; j < ONUM; ++j)
            acc[j] = fmaf(fv, Wm[(o_lo + j) * C + c], acc[j]);
    }
#pragma unroll
    for (int j = 0; j < ONUM; ++j)
        acc[j] = __builtin_amdgcn_rcpf(1.0f + __expf(-acc[j]));
    constexpr float S = (float)(8 << LEVEL);
    constexpr int AOFF = (LEVEL == 0) ? 0 : ((LEVEL == 1) ? 6400 : 8000);
    float* op = out + ((size_t)b * 8400 + AOFF + hw) * 85 + o_lo;
    if constexpr (BOX) {
        constexpr float P4 = 4.0f * (float)(1 << LEVEL);
        float wx = (float)(hw % NX), wy = (float)(hw / NX);
        float d0 = acc[0] * acc[0] * P4, d1 = acc[1] * acc[1] * P4;
        float d2 = acc[2] * acc[2] * P4, d3 = acc[3] * acc[3] * P4;
        float x1 = (wx + 1.0f - d0) * S, y1 = (wy + 1.0f - d1) * S;
        float x2 = (wx + d2) * S,        y2 = (wy + d3) * S;
        op[0] = (x1 + x2) * 0.5f; op[1] = (y1 + y2) * 0.5f;
        op[2] = x2 - x1;          op[3] = y2 - y1;
#pragma unroll
        for (int j = 4; j < ONUM; ++j) op[j] = acc[j];
    } else {
#pragma unroll
        for (int j = 0; j < ONUM; ++j) op[j] = acc[j];
    }
}

template <int C, int HW, int NX, int LEVEL>
__device__ __forceinline__ void level_block_fb(
    const float* __restrict__ feat, const float* __restrict__ Wm,
    const float* __restrict__ bias, float* __restrict__ out, int bb)
{
    const int wave = threadIdx.x >> 6, lane = threadIdx.x & 63;
    const int pos = bb * 64 + lane;
    if      (wave == 0) decode_path_fb<C, HW, NX, LEVEL, 22, true >(feat, Wm, bias, out, 0,  pos);
    else if (wave == 1) decode_path_fb<C, HW, NX, LEVEL, 22, false>(feat, Wm, bias, out, 22, pos);
    else if (wave == 2) decode_path_fb<C, HW, NX, LEVEL, 22, false>(feat, Wm, bias, out, 44, pos);
    else                decode_path_fb<C, HW, NX, LEVEL, 19, false>(feat, Wm, bias, out, 66, pos);
}

__global__ __launch_bounds__(256) void detect_fallback(
    const float* __restrict__ x0, const float* __restrict__ x1,
    const float* __restrict__ x2,
    const float* __restrict__ w0, const float* __restrict__ w1,
    const float* __restrict__ w2,
    const float* __restrict__ b0, const float* __restrict__ b1,
    const float* __restrict__ b2, float* __restrict__ out)
{
    const int blk = blockIdx.x;
    if (blk < 100)      level_block_fb<1024, 400,  20, 2>(x2, w2, b2, out, blk);
    else if (blk < 500) level_block_fb<512,  1600, 40, 1>(x1, w1, b1, out, blk - 100);
    else                level_block_fb<256,  6400, 80, 0>(x0, w0, b0, out, blk - 500);
}

extern "C" void kernel_launch(void* const* d_in, const int* in_sizes, int n_in,
                              void* d_out, int out_size, void* d_ws, size_t ws_size,
                              hipStream_t stream)
{
    const float* x0 = (const float*)d_in[0];
    const float* x1 = (const float*)d_in[1];
    const float* x2 = (const float*)d_in[2];
    const float* W0 = (const float*)d_in[3];
    const float* b0 = (const float*)d_in[4];
    const float* W1 = (const float*)d_in[5];
    const float* b1 = (const float*)d_in[6];
    const float* W2 = (const float*)d_in[7];
    const float* b2 = (const float*)d_in[8];
    float* out = (float*)d_out;

    if (ws_size >= WS_NEED) {
        unsigned char* ws = (unsigned char*)d_ws;
        prep_pack<<<(NFRAG * 64 + 255) / 256, 256, 0, stream>>>(W0, W1, W2, b0, b1, b2, ws);
        detect_mfma<<<2100, 256, 0, stream>>>(x0, x1, x2, ws, out);
    } else {
        detect_fallback<<<2100, 256, 0, stream>>>(x0, x1, x2, W0, W1, W2, b0, b1, b2, out);
    }
}

// Round 10
// 48.344 us; speedup vs baseline: 3.1329x; 1.0002x over previous
//
#include <hip/hip_runtime.h>
#include <cstdint>

// ---------------------------------------------------------------------------
// ObjectBoxDetect via bf16 MFMA. out[16,8400,85] fp32.
//   L0: x[16,256,80,80]  W[85,256]  stride 8   anchors [0,6400)
//   L1: x[16,512,40,40]  W[85,512]  stride 16  anchors [6400,8000)
//   L2: x[16,1024,20,20] W[85,1024] stride 32  anchors [8000,8400)
//
// Round-10: r6==r9 (depth-1 == depth-2 prefetch) exposed the real serializer:
// __syncthreads() emits s_waitcnt vmcnt(0) before s_barrier, draining the
// A/B register prefetches at EVERY kstep barrier (m97-structure stall).
// Fix: s_waitcnt lgkmcnt(0) + raw s_barrier (HK/m201 pattern) -- LDS writes
// are visible to the block, register-destined global loads stay in flight.
// Geometry/pipeline identical to r9 (48.4us, no spill, absmax 4.0).
// ---------------------------------------------------------------------------

typedef __attribute__((ext_vector_type(8))) short bf16x8;
typedef __attribute__((ext_vector_type(4))) float f32x4;

constexpr int KS0 = 8, KS1 = 16, KS2 = 32;            // K-steps per level (C/32)
constexpr int F0 = 6 * KS0, F1 = 6 * KS1, F2 = 6 * KS2;
constexpr int FOFF0 = 0, FOFF1 = F0, FOFF2 = F0 + F1;
constexpr int NFRAG = F0 + F1 + F2;                    // 336 fragments
constexpr size_t BIAS_OFF = 0;                         // 3*96 floats = 1152 B
constexpr size_t BPK_OFF  = 1152;                      // 16B aligned
constexpr size_t WS_NEED  = BPK_OFF + (size_t)NFRAG * 64 * 16;

__device__ __forceinline__ unsigned short f2bf(float f) {
    union { float f; unsigned u; } v; v.f = f;
    unsigned r = v.u + 0x7FFF + ((v.u >> 16) & 1);     // round-to-nearest-even
    return (unsigned short)(r >> 16);
}

// Barrier that does NOT drain vmcnt: LDS traffic settled (lgkmcnt 0), raw
// s_barrier; register-destined global prefetches stay in flight (T3/T4).
__device__ __forceinline__ void barrier_keep_vmcnt() {
    asm volatile("s_waitcnt lgkmcnt(0)" ::: "memory");
    __builtin_amdgcn_s_barrier();
}

// Pack W[o][c] -> bf16 B-fragments ([ks][n]-major per level) + padded bias.
// B frag layout (16x16x32): lane l holds col o = n*16+(l&15),
// k-slots c = ks*32 + (l>>4)*8 + e.
__global__ __launch_bounds__(256) void prep_pack(
    const float* __restrict__ W0, const float* __restrict__ W1,
    const float* __restrict__ W2,
    const float* __restrict__ b0, const float* __restrict__ b1,
    const float* __restrict__ b2,
    unsigned char* __restrict__ ws)
{
    int t = blockIdx.x * 256 + threadIdx.x;
    if (t < 288) {
        int lvl = t / 96, o = t % 96;
        const float* bp = (lvl == 0) ? b0 : (lvl == 1) ? b1 : b2;
        ((float*)(ws + BIAS_OFF))[t] = (o < 85) ? bp[o] : 0.0f;
    }
    if (t >= NFRAG * 64) return;
    int frag = t >> 6, l = t & 63;
    int C; const float* W; int f;
    if (frag < FOFF1)      { C = 256;  W = W0; f = frag;         }
    else if (frag < FOFF2) { C = 512;  W = W1; f = frag - FOFF1; }
    else                   { C = 1024; W = W2; f = frag - FOFF2; }
    int ks = f / 6, n = f % 6;                          // [ks][n]-major
    int o  = n * 16 + (l & 15);
    int c0 = ks * 32 + (l >> 4) * 8;
    bf16x8 r;
#pragma unroll
    for (int e = 0; e < 8; ++e)
        r[e] = (o < 85) ? (short)f2bf(W[(size_t)o * C + c0 + e]) : (short)0;
    ((bf16x8*)(ws + BPK_OFF))[frag * 64 + l] = r;
}

template <int C, int HW, int NX, int LEVEL, int AOFF, int KSTEPS, int FOFF>
__device__ __forceinline__ void mfma_level(
    const float* __restrict__ feat, const unsigned char* __restrict__ ws,
    float* __restrict__ out, int blk, uint4* __restrict__ Bsm /* [2][384] */)
{
    const int tid = threadIdx.x;
    const int w   = tid >> 6;
    const int l   = tid & 63;
    const int col = l & 15;            // output col within 16-tile
    const int kg  = l >> 4;            // k-group
    const bool lo_half = (tid < 128);  // uniform per wave

    // one 16-pos M-subtile per wave; HW % 16 == 0 so it stays in one batch.
    const int p0  = blk * 64 + w * 16;
    const int b   = p0 / HW;
    const int hw0 = p0 - b * HW;
    const float* fb = feat + (size_t)b * C * HW + hw0;
    const float* pA = fb + col + (size_t)(kg * 8) * HW;   // per-lane A base

    const float* bias = (const float*)(ws + BIAS_OFF) + LEVEL * 96;
    const uint4* bsrc = (const uint4*)(ws + BPK_OFF) + (size_t)FOFF * 64;

    f32x4 acc[6];
#pragma unroll
    for (int n = 0; n < 6; ++n) {
        float bv = bias[n * 16 + col];
        f32x4 z = { bv, bv, bv, bv };
        acc[n] = z;
    }

    uint4* buf0 = Bsm;
    uint4* buf1 = Bsm + 384;

    // ---- prologue ----
    // B(0) straight into LDS buf0
    {
        const uint4* s = bsrc;
        buf0[tid] = s[tid];
        if (lo_half) buf0[256 + tid] = s[256 + tid];
    }
    // A(0) -> flA0, A(1) -> flA1
    float flA0[8], flA1[8];
#pragma unroll
    for (int e = 0; e < 8; ++e) flA0[e] = pA[(size_t)e * HW];
    if (KSTEPS > 1) {
        const float* p = pA + (size_t)32 * HW;
#pragma unroll
        for (int e = 0; e < 8; ++e) flA1[e] = p[(size_t)e * HW];
    }
    // B(1) -> pend regs (ds_written inside even step 0)
    uint4 pb0, pb1;
    if (KSTEPS > 1) {
        const uint4* s = bsrc + 384;
        pb0 = s[tid];
        if (lo_half) pb1 = s[256 + tid];
    }
    barrier_keep_vmcnt();

#pragma unroll 1
    for (int ks = 0; ks < KSTEPS; ks += 2) {   // KSTEPS even for all levels
        // ================= even step: consume buf0 / flA0 =================
        // 1. ds_write pend B(ks+1) (issued a full step ago) -> buf1
        if (ks + 1 < KSTEPS) {
            buf1[tid] = pb0;
            if (lo_half) buf1[256 + tid] = pb1;
        }
        // 2. issue B(ks+2) -> pend regs
        if (ks + 2 < KSTEPS) {
            const uint4* s = bsrc + (size_t)(ks + 2) * 384;
            pb0 = s[tid];
            if (lo_half) pb1 = s[256 + tid];
        }
        // 3. cvt A(ks)
        {
            bf16x8 a;
#pragma unroll
            for (int e = 0; e < 8; ++e) a[e] = (short)f2bf(flA0[e]);
            // 4. issue A(ks+2) into the slot just consumed
            if (ks + 2 < KSTEPS) {
                const float* p = pA + (size_t)((ks + 2) * 32) * HW;
#pragma unroll
                for (int e = 0; e < 8; ++e) flA0[e] = p[(size_t)e * HW];
            }
            // 5. MFMA from buf0
            const bf16x8* bl = (const bf16x8*)buf0;
#pragma unroll
            for (int n = 0; n < 6; ++n) {
                bf16x8 bq = bl[n * 64 + l];
                acc[n] = __builtin_amdgcn_mfma_f32_16x16x32_bf16(a, bq, acc[n], 0, 0, 0);
            }
        }
        barrier_keep_vmcnt();

        // ================= odd step: consume buf1 / flA1 ==================
        // 1. ds_write pend B(ks+2) -> buf0
        if (ks + 2 < KSTEPS) {
            buf0[tid] = pb0;
            if (lo_half) buf0[256 + tid] = pb1;
        }
        // 2. issue B(ks+3) -> pend regs
        if (ks + 3 < KSTEPS) {
            const uint4* s = bsrc + (size_t)(ks + 3) * 384;
            pb0 = s[tid];
            if (lo_half) pb1 = s[256 + tid];
        }
        // 3. cvt A(ks+1)
        if (ks + 1 < KSTEPS) {
            bf16x8 a;
#pragma unroll
            for (int e = 0; e < 8; ++e) a[e] = (short)f2bf(flA1[e]);
            // 4. issue A(ks+3)
            if (ks + 3 < KSTEPS) {
                const float* p = pA + (size_t)((ks + 3) * 32) * HW;
#pragma unroll
                for (int e = 0; e < 8; ++e) flA1[e] = p[(size_t)e * HW];
            }
            // 5. MFMA from buf1
            const bf16x8* bl = (const bf16x8*)buf1;
#pragma unroll
            for (int n = 0; n < 6; ++n) {
                bf16x8 bq = bl[n * 64 + l];
                acc[n] = __builtin_amdgcn_mfma_f32_16x16x32_bf16(a, bq, acc[n], 0, 0, 0);
            }
        }
        barrier_keep_vmcnt();
    }

    // Epilogue. C/D layout (m89-verified): col = l&15, row = (l>>4)*4 + j.
    constexpr float S  = (float)(8 << LEVEL);
    constexpr float P4 = 4.0f * (float)(1 << LEVEL);
#pragma unroll
    for (int j = 0; j < 4; ++j) {
        const int hw = hw0 + kg * 4 + j;
        float sg[6];
#pragma unroll
        for (int n = 0; n < 6; ++n) {
            float v = acc[n][j];
            sg[n] = __builtin_amdgcn_rcpf(1.0f + __expf(-v));
        }
        const int grp = l & 48;
        float y0 = __shfl(sg[0], grp + 0);
        float y1 = __shfl(sg[0], grp + 1);
        float y2 = __shfl(sg[0], grp + 2);
        float y3 = __shfl(sg[0], grp + 3);
        float wx = (float)(hw % NX);
        float wy = (float)(hw / NX);
        float d0 = y0 * y0 * P4, d1 = y1 * y1 * P4;
        float d2 = y2 * y2 * P4, d3 = y3 * y3 * P4;
        float x1 = (wx + 1.0f - d0) * S;
        float yA = (wy + 1.0f - d1) * S;
        float x2 = (wx + d2) * S;
        float yB = (wy + d3) * S;
        float bx = (x1 + x2) * 0.5f, by = (yA + yB) * 0.5f;
        float bw = x2 - x1,          bh = yB - yA;
        sg[0] = (col == 0) ? bx : (col == 1) ? by
              : (col == 2) ? bw : (col == 3) ? bh : sg[0];
        float* op = out + ((size_t)b * 8400 + AOFF + hw) * 85;
#pragma unroll
        for (int n = 0; n < 6; ++n) {
            int o = n * 16 + col;
            if (o < 85) op[o] = sg[n];
        }
    }
}

// Grid: 2100 blocks of 64 positions, heaviest-first (longest-job-first:
// all 100 L2 blocks, 32 ksteps each, dispatch at t=0).
__global__ __launch_bounds__(256, 6) void detect_mfma(
    const float* __restrict__ x0, const float* __restrict__ x1,
    const float* __restrict__ x2,
    const unsigned char* __restrict__ ws, float* __restrict__ out)
{
    __shared__ uint4 Bsm[2 * 384];     // 12 KB double-buffered B stage
    int blk = blockIdx.x;
    if (blk < 100)      mfma_level<1024, 400,  20, 2, 8000, KS2, FOFF2>(x2, ws, out, blk,       Bsm);
    else if (blk < 500) mfma_level<512,  1600, 40, 1, 6400, KS1, FOFF1>(x1, ws, out, blk - 100, Bsm);
    else                mfma_level<256,  6400, 80, 0, 0,    KS0, FOFF0>(x0, ws, out, blk - 500, Bsm);
}

// ---------------- fallback (ws too small): round-2 VALU path ----------------
template <int C, int HW, int NX, int LEVEL, int ONUM, bool BOX>
__device__ __forceinline__ void decode_path_fb(
    const float* __restrict__ feat, const float* __restrict__ Wm,
    const float* __restrict__ bias, float* __restrict__ out,
    int o_lo_in, int pos)
{
    const int o_lo = __builtin_amdgcn_readfirstlane(o_lo_in);
    const int b  = pos / HW;
    const int hw = pos - b * HW;
    const float* fp = feat + (size_t)b * (C * HW) + hw;
    float acc[ONUM];
#pragma unroll
    for (int j = 0; j < ONUM; ++j) acc[j] = bias[o_lo + j];
#pragma unroll 4
    for (int c = 0; c < C; ++c) {
        float fv = fp[(size_t)c * HW];
#pragma unroll
        for (int j = 0; j < ONUM; ++j)
            acc[j] = fmaf(fv, Wm[(o_lo + j) * C + c], acc[j]);
    }
#pragma unroll
    for (int j = 0; j < ONUM; ++j)
        acc[j] = __builtin_amdgcn_rcpf(1.0f + __expf(-acc[j]));
    constexpr float S = (float)(8 << LEVEL);
    constexpr int AOFF = (LEVEL == 0) ? 0 : ((LEVEL == 1) ? 6400 : 8000);
    float* op = out + ((size_t)b * 8400 + AOFF + hw) * 85 + o_lo;
    if constexpr (BOX) {
        constexpr float P4 = 4.0f * (float)(1 << LEVEL);
        float wx = (float)(hw % NX), wy = (float)(hw / NX);
        float d0 = acc[0] * acc[0] * P4, d1 = acc[1] * acc[1] * P4;
        float d2 = acc[2] * acc[2] * P4, d3 = acc[3] * acc[3] * P4;
        float x1 = (wx + 1.0f - d0) * S, y1 = (wy + 1.0f - d1) * S;
        float x2 = (wx + d2) * S,        y2 = (wy + d3) * S;
        op[0] = (x1 + x2) * 0.5f; op[1] = (y1 + y2) * 0.5f;
        op[2] = x2 - x1;          op[3] = y2 - y1;
#pragma unroll
        for (int j = 4; j < ONUM; ++j) op[j] = acc[j];
    } else {
#pragma unroll
        for (int j = 0; j < ONUM; ++j) op[j] = acc[j];
    }
}

template <int C, int HW, int NX, int LEVEL>
__device__ __forceinline__ void level_block_fb(
    const float* __restrict__ feat, const float* __restrict__ Wm,
    const float* __restrict__ bias, float* __restrict__ out, int bb)
{
    const int wave = threadIdx.x >> 6, lane = threadIdx.x & 63;
    const int pos = bb * 64 + lane;
    if      (wave == 0) decode_path_fb<C, HW, NX, LEVEL, 22, true >(feat, Wm, bias, out, 0,  pos);
    else if (wave == 1) decode_path_fb<C, HW, NX, LEVEL, 22, false>(feat, Wm, bias, out, 22, pos);
    else if (wave == 2) decode_path_fb<C, HW, NX, LEVEL, 22, false>(feat, Wm, bias, out, 44, pos);
    else                decode_path_fb<C, HW, NX, LEVEL, 19, false>(feat, Wm, bias, out, 66, pos);
}

__global__ __launch_bounds__(256) void detect_fallback(
    const float* __restrict__ x0, const float* __restrict__ x1,
    const float* __restrict__ x2,
    const float* __restrict__ w0, const float* __restrict__ w1,
    const float* __restrict__ w2,
    const float* __restrict__ b0, const float* __restrict__ b1,
    const float* __restrict__ b2, float* __restrict__ out)
{
    const int blk = blockIdx.x;
    if (blk < 100)      level_block_fb<1024, 400,  20, 2>(x2, w2, b2, out, blk);
    else if (blk < 500) level_block_fb<512,  1600, 40, 1>(x1, w1, b1, out, blk - 100);
    else                level_block_fb<256,  6400, 80, 0>(x0, w0, b0, out, blk - 500);
}

extern "C" void kernel_launch(void* const* d_in, const int* in_sizes, int n_in,
                              void* d_out, int out_size, void* d_ws, size_t ws_size,
                              hipStream_t stream)
{
    const float* x0 = (const float*)d_in[0];
    const float* x1 = (const float*)d_in[1];
    const float* x2 = (const float*)d_in[2];
    const float* W0 = (const float*)d_in[3];
    const float* b0 = (const float*)d_in[4];
    const float* W1 = (const float*)d_in[5];
    const float* b1 = (const float*)d_in[6];
    const float* W2 = (const float*)d_in[7];
    const float* b2 = (const float*)d_in[8];
    float* out = (float*)d_out;

    if (ws_size >= WS_NEED) {
        unsigned char* ws = (unsigned char*)d_ws;
        prep_pack<<<(NFRAG * 64 + 255) / 256, 256, 0, stream>>>(W0, W1, W2, b0, b1, b2, ws);
        detect_mfma<<<2100, 256, 0, stream>>>(x0, x1, x2, ws, out);
    } else {
        detect_fallback<<<2100, 256, 0, stream>>>(x0, x1, x2, W0, W1, W2, b0, b1, b2, out);
    }
}